// Round 12
// baseline (158.455 us; speedup 1.0000x reference)
//
#include <hip/hip_runtime.h>

// out_f32[t,i,d] = x[t,d]*plm[t,i] + sum_j comb[t,j,i]*res[t,j,d]
// T=8192, HC=4, H=2560. ALL device buffers are f32 (proven R0-R8).
//
// Round-12: A/B experiment vs R11 (147.2 us, 5.14 TB/s logical, 82% of the
// 6.29 TB/s copy ceiling). 2 tokens per block: 4096 blocks (half the ramp),
// x-read becomes one 20 KB contiguous run, 20 loads in flight per thread.
// MLP analysis says parallelism is already sufficient, so this isolates
// stream-structure/dispatch-ramp effects. Null result => ROOFLINE.

#define HIDDEN 2560
#define HC 4
#define D8 (HIDDEN / 8)   // 320 threads/block, 5 waves

__global__ __launch_bounds__(D8) void fused_mix_f32_x2(
    const float* __restrict__ x,     // [T, H]
    const float* __restrict__ res,   // [T, HC, H]
    const float* __restrict__ plm,   // [T, HC]
    const float* __restrict__ comb,  // [T, HC, HC]  comb[t][j][i]
    float* __restrict__ out)         // [T, HC, H]
{
    const long t0 = (long)blockIdx.x * 2;
    const long t1 = t0 + 1;
    const int  d8 = threadIdx.x;     // 0..319, 8 f32 per token

    // Block-uniform coefficients (scalar path)
    const float4 Ac0 = *reinterpret_cast<const float4*>(comb + t0 * 16 + 0);
    const float4 Ac1 = *reinterpret_cast<const float4*>(comb + t0 * 16 + 4);
    const float4 Ac2 = *reinterpret_cast<const float4*>(comb + t0 * 16 + 8);
    const float4 Ac3 = *reinterpret_cast<const float4*>(comb + t0 * 16 + 12);
    const float4 Ap  = *reinterpret_cast<const float4*>(plm  + t0 * 4);
    const float4 Bc0 = *reinterpret_cast<const float4*>(comb + t1 * 16 + 0);
    const float4 Bc1 = *reinterpret_cast<const float4*>(comb + t1 * 16 + 4);
    const float4 Bc2 = *reinterpret_cast<const float4*>(comb + t1 * 16 + 8);
    const float4 Bc3 = *reinterpret_cast<const float4*>(comb + t1 * 16 + 12);
    const float4 Bp  = *reinterpret_cast<const float4*>(plm  + t1 * 4);

    const long xoff0  = t0 * HIDDEN + (long)d8 * 8;
    const long xoff1  = t1 * HIDDEN + (long)d8 * 8;
    const long rbase0 = t0 * (HC * HIDDEN) + (long)d8 * 8;
    const long rbase1 = t1 * (HC * HIDDEN) + (long)d8 * 8;

    // Issue all 20 vector loads up front (both tokens deep in flight).
    const float4 Axa  = *reinterpret_cast<const float4*>(x + xoff0);
    const float4 Axb  = *reinterpret_cast<const float4*>(x + xoff0 + 4);
    const float4 Ar0a = *reinterpret_cast<const float4*>(res + rbase0 + 0 * HIDDEN);
    const float4 Ar0b = *reinterpret_cast<const float4*>(res + rbase0 + 0 * HIDDEN + 4);
    const float4 Ar1a = *reinterpret_cast<const float4*>(res + rbase0 + 1 * HIDDEN);
    const float4 Ar1b = *reinterpret_cast<const float4*>(res + rbase0 + 1 * HIDDEN + 4);
    const float4 Ar2a = *reinterpret_cast<const float4*>(res + rbase0 + 2 * HIDDEN);
    const float4 Ar2b = *reinterpret_cast<const float4*>(res + rbase0 + 2 * HIDDEN + 4);
    const float4 Ar3a = *reinterpret_cast<const float4*>(res + rbase0 + 3 * HIDDEN);
    const float4 Ar3b = *reinterpret_cast<const float4*>(res + rbase0 + 3 * HIDDEN + 4);
    const float4 Bxa  = *reinterpret_cast<const float4*>(x + xoff1);
    const float4 Bxb  = *reinterpret_cast<const float4*>(x + xoff1 + 4);
    const float4 Br0a = *reinterpret_cast<const float4*>(res + rbase1 + 0 * HIDDEN);
    const float4 Br0b = *reinterpret_cast<const float4*>(res + rbase1 + 0 * HIDDEN + 4);
    const float4 Br1a = *reinterpret_cast<const float4*>(res + rbase1 + 1 * HIDDEN);
    const float4 Br1b = *reinterpret_cast<const float4*>(res + rbase1 + 1 * HIDDEN + 4);
    const float4 Br2a = *reinterpret_cast<const float4*>(res + rbase1 + 2 * HIDDEN);
    const float4 Br2b = *reinterpret_cast<const float4*>(res + rbase1 + 2 * HIDDEN + 4);
    const float4 Br3a = *reinterpret_cast<const float4*>(res + rbase1 + 3 * HIDDEN);
    const float4 Br3b = *reinterpret_cast<const float4*>(res + rbase1 + 3 * HIDDEN + 4);

    #define MIX4(XX, R0, R1, R2, R3, PI, C0I, C1I, C2I, C3I)                  \
        make_float4(                                                           \
            XX.x * PI + C0I * R0.x + C1I * R1.x + C2I * R2.x + C3I * R3.x,     \
            XX.y * PI + C0I * R0.y + C1I * R1.y + C2I * R2.y + C3I * R3.y,     \
            XX.z * PI + C0I * R0.z + C1I * R1.z + C2I * R2.z + C3I * R3.z,     \
            XX.w * PI + C0I * R0.w + C1I * R1.w + C2I * R2.w + C3I * R3.w)

    float* opA = out + rbase0;
    *reinterpret_cast<float4*>(opA + 0 * HIDDEN)     = MIX4(Axa, Ar0a, Ar1a, Ar2a, Ar3a, Ap.x, Ac0.x, Ac1.x, Ac2.x, Ac3.x);
    *reinterpret_cast<float4*>(opA + 0 * HIDDEN + 4) = MIX4(Axb, Ar0b, Ar1b, Ar2b, Ar3b, Ap.x, Ac0.x, Ac1.x, Ac2.x, Ac3.x);
    *reinterpret_cast<float4*>(opA + 1 * HIDDEN)     = MIX4(Axa, Ar0a, Ar1a, Ar2a, Ar3a, Ap.y, Ac0.y, Ac1.y, Ac2.y, Ac3.y);
    *reinterpret_cast<float4*>(opA + 1 * HIDDEN + 4) = MIX4(Axb, Ar0b, Ar1b, Ar2b, Ar3b, Ap.y, Ac0.y, Ac1.y, Ac2.y, Ac3.y);
    *reinterpret_cast<float4*>(opA + 2 * HIDDEN)     = MIX4(Axa, Ar0a, Ar1a, Ar2a, Ar3a, Ap.z, Ac0.z, Ac1.z, Ac2.z, Ac3.z);
    *reinterpret_cast<float4*>(opA + 2 * HIDDEN + 4) = MIX4(Axb, Ar0b, Ar1b, Ar2b, Ar3b, Ap.z, Ac0.z, Ac1.z, Ac2.z, Ac3.z);
    *reinterpret_cast<float4*>(opA + 3 * HIDDEN)     = MIX4(Axa, Ar0a, Ar1a, Ar2a, Ar3a, Ap.w, Ac0.w, Ac1.w, Ac2.w, Ac3.w);
    *reinterpret_cast<float4*>(opA + 3 * HIDDEN + 4) = MIX4(Axb, Ar0b, Ar1b, Ar2b, Ar3b, Ap.w, Ac0.w, Ac1.w, Ac2.w, Ac3.w);

    float* opB = out + rbase1;
    *reinterpret_cast<float4*>(opB + 0 * HIDDEN)     = MIX4(Bxa, Br0a, Br1a, Br2a, Br3a, Bp.x, Bc0.x, Bc1.x, Bc2.x, Bc3.x);
    *reinterpret_cast<float4*>(opB + 0 * HIDDEN + 4) = MIX4(Bxb, Br0b, Br1b, Br2b, Br3b, Bp.x, Bc0.x, Bc1.x, Bc2.x, Bc3.x);
    *reinterpret_cast<float4*>(opB + 1 * HIDDEN)     = MIX4(Bxa, Br0a, Br1a, Br2a, Br3a, Bp.y, Bc0.y, Bc1.y, Bc2.y, Bc3.y);
    *reinterpret_cast<float4*>(opB + 1 * HIDDEN + 4) = MIX4(Bxb, Br0b, Br1b, Br2b, Br3b, Bp.y, Bc0.y, Bc1.y, Bc2.y, Bc3.y);
    *reinterpret_cast<float4*>(opB + 2 * HIDDEN)     = MIX4(Bxa, Br0a, Br1a, Br2a, Br3a, Bp.z, Bc0.z, Bc1.z, Bc2.z, Bc3.z);
    *reinterpret_cast<float4*>(opB + 2 * HIDDEN + 4) = MIX4(Bxb, Br0b, Br1b, Br2b, Br3b, Bp.z, Bc0.z, Bc1.z, Bc2.z, Bc3.z);
    *reinterpret_cast<float4*>(opB + 3 * HIDDEN)     = MIX4(Bxa, Br0a, Br1a, Br2a, Br3a, Bp.w, Bc0.w, Bc1.w, Bc2.w, Bc3.w);
    *reinterpret_cast<float4*>(opB + 3 * HIDDEN + 4) = MIX4(Bxb, Br0b, Br1b, Br2b, Br3b, Bp.w, Bc0.w, Bc1.w, Bc2.w, Bc3.w);
    #undef MIX4
}

extern "C" void kernel_launch(void* const* d_in, const int* in_sizes, int n_in,
                              void* d_out, int out_size, void* d_ws, size_t ws_size,
                              hipStream_t stream) {
    const long T = (long)out_size / ((long)HC * HIDDEN);   // 8192

    const long n_x = T * HIDDEN, n_r = T * HC * HIDDEN, n_p = T * HC, n_c = T * HC * HC;
    const float* x = nullptr; const float* res = nullptr;
    const float* plm = nullptr; const float* comb = nullptr;
    for (int i = 0; i < n_in; ++i) {
        const long sz = in_sizes[i];
        if      (sz == n_x) x    = (const float*)d_in[i];
        else if (sz == n_r) res  = (const float*)d_in[i];
        else if (sz == n_p) plm  = (const float*)d_in[i];
        else if (sz == n_c) comb = (const float*)d_in[i];
    }
    if (!x || !res || !plm || !comb) {
        x    = (const float*)d_in[0];
        res  = (const float*)d_in[1];
        plm  = (const float*)d_in[2];
        comb = (const float*)d_in[3];
    }

    fused_mix_f32_x2<<<(int)(T / 2), D8, 0, stream>>>(x, res, plm, comb, (float*)d_out);
}

// Round 13
// 147.109 us; speedup vs baseline: 1.0771x; 1.0771x over previous
//
#include <hip/hip_runtime.h>

// out_f32[t,i,d] = x[t,d]*plm[t,i] + sum_j comb[t,j,i]*res[t,j,d]
// T=8192, HC=4, H=2560. ALL device buffers are f32 (proven R0-R8).
//
// Round-13: REVERT to the round-11 kernel (best measured: 147.2 us,
// 5.14 TB/s logical = 82% of the 6.29 TB/s copy ceiling).
// A/B history: +nontemporal -> 214 us (write amplification 336->536 MB);
// 2 tokens/block -> 158 us (register-serialized issue, no BW gain).
// 1 token/block, 320 threads, 10 float4 loads / 8 float4 stores per thread,
// block-uniform scalar coeff loads. This is the mixed-stream DRAM roofline:
// 756 MB @ ~82% of copy BW ~= 147 us.

#define HIDDEN 2560
#define HC 4
#define D8 (HIDDEN / 8)   // 320 threads/block, 5 waves

__global__ __launch_bounds__(D8) void fused_mix_f32(
    const float* __restrict__ x,     // [T, H]
    const float* __restrict__ res,   // [T, HC, H]
    const float* __restrict__ plm,   // [T, HC]
    const float* __restrict__ comb,  // [T, HC, HC]  comb[t][j][i]
    float* __restrict__ out)         // [T, HC, H]
{
    const long t  = blockIdx.x;
    const int  d8 = threadIdx.x;     // 0..319, 8 f32 each

    // Block-uniform coefficients -> scalar (s_load) path.
    const float4 c0 = *reinterpret_cast<const float4*>(comb + t * 16 + 0);   // row j=0
    const float4 c1 = *reinterpret_cast<const float4*>(comb + t * 16 + 4);   // row j=1
    const float4 c2 = *reinterpret_cast<const float4*>(comb + t * 16 + 8);   // row j=2
    const float4 c3 = *reinterpret_cast<const float4*>(comb + t * 16 + 12);  // row j=3
    const float4 p  = *reinterpret_cast<const float4*>(plm  + t * 4);

    const long xoff  = t * HIDDEN + (long)d8 * 8;
    const long rbase = t * (HC * HIDDEN) + (long)d8 * 8;

    // Issue all 10 vector loads up front (independent -> deep in flight).
    const float4 xa  = *reinterpret_cast<const float4*>(x + xoff);
    const float4 xb  = *reinterpret_cast<const float4*>(x + xoff + 4);
    const float4 r0a = *reinterpret_cast<const float4*>(res + rbase + 0 * HIDDEN);
    const float4 r0b = *reinterpret_cast<const float4*>(res + rbase + 0 * HIDDEN + 4);
    const float4 r1a = *reinterpret_cast<const float4*>(res + rbase + 1 * HIDDEN);
    const float4 r1b = *reinterpret_cast<const float4*>(res + rbase + 1 * HIDDEN + 4);
    const float4 r2a = *reinterpret_cast<const float4*>(res + rbase + 2 * HIDDEN);
    const float4 r2b = *reinterpret_cast<const float4*>(res + rbase + 2 * HIDDEN + 4);
    const float4 r3a = *reinterpret_cast<const float4*>(res + rbase + 3 * HIDDEN);
    const float4 r3b = *reinterpret_cast<const float4*>(res + rbase + 3 * HIDDEN + 4);

    // out_i = x*p[i] + c0[i]*r0 + c1[i]*r1 + c2[i]*r2 + c3[i]*r3
    #define MIX4(XX, R0, R1, R2, R3, PI, C0I, C1I, C2I, C3I)                  \
        make_float4(                                                           \
            XX.x * PI + C0I * R0.x + C1I * R1.x + C2I * R2.x + C3I * R3.x,     \
            XX.y * PI + C0I * R0.y + C1I * R1.y + C2I * R2.y + C3I * R3.y,     \
            XX.z * PI + C0I * R0.z + C1I * R1.z + C2I * R2.z + C3I * R3.z,     \
            XX.w * PI + C0I * R0.w + C1I * R1.w + C2I * R2.w + C3I * R3.w)

    float* op = out + rbase;
    *reinterpret_cast<float4*>(op + 0 * HIDDEN)     = MIX4(xa, r0a, r1a, r2a, r3a, p.x, c0.x, c1.x, c2.x, c3.x);
    *reinterpret_cast<float4*>(op + 0 * HIDDEN + 4) = MIX4(xb, r0b, r1b, r2b, r3b, p.x, c0.x, c1.x, c2.x, c3.x);
    *reinterpret_cast<float4*>(op + 1 * HIDDEN)     = MIX4(xa, r0a, r1a, r2a, r3a, p.y, c0.y, c1.y, c2.y, c3.y);
    *reinterpret_cast<float4*>(op + 1 * HIDDEN + 4) = MIX4(xb, r0b, r1b, r2b, r3b, p.y, c0.y, c1.y, c2.y, c3.y);
    *reinterpret_cast<float4*>(op + 2 * HIDDEN)     = MIX4(xa, r0a, r1a, r2a, r3a, p.z, c0.z, c1.z, c2.z, c3.z);
    *reinterpret_cast<float4*>(op + 2 * HIDDEN + 4) = MIX4(xb, r0b, r1b, r2b, r3b, p.z, c0.z, c1.z, c2.z, c3.z);
    *reinterpret_cast<float4*>(op + 3 * HIDDEN)     = MIX4(xa, r0a, r1a, r2a, r3a, p.w, c0.w, c1.w, c2.w, c3.w);
    *reinterpret_cast<float4*>(op + 3 * HIDDEN + 4) = MIX4(xb, r0b, r1b, r2b, r3b, p.w, c0.w, c1.w, c2.w, c3.w);
    #undef MIX4
}

extern "C" void kernel_launch(void* const* d_in, const int* in_sizes, int n_in,
                              void* d_out, int out_size, void* d_ws, size_t ws_size,
                              hipStream_t stream) {
    const long T = (long)out_size / ((long)HC * HIDDEN);   // 8192

    // Element-count matching (counts are dtype-independent); positional fallback.
    const long n_x = T * HIDDEN, n_r = T * HC * HIDDEN, n_p = T * HC, n_c = T * HC * HC;
    const float* x = nullptr; const float* res = nullptr;
    const float* plm = nullptr; const float* comb = nullptr;
    for (int i = 0; i < n_in; ++i) {
        const long sz = in_sizes[i];
        if      (sz == n_x) x    = (const float*)d_in[i];
        else if (sz == n_r) res  = (const float*)d_in[i];
        else if (sz == n_p) plm  = (const float*)d_in[i];
        else if (sz == n_c) comb = (const float*)d_in[i];
    }
    if (!x || !res || !plm || !comb) {
        x    = (const float*)d_in[0];
        res  = (const float*)d_in[1];
        plm  = (const float*)d_in[2];
        comb = (const float*)d_in[3];
    }

    fused_mix_f32<<<(int)T, D8, 0, stream>>>(x, res, plm, comb, (float*)d_out);
}